// Round 5
// baseline (195153.918 us; speedup 1.0000x reference)
//
#include <hip/hip_runtime.h>
#include <stdint.h>

// ---------------------------------------------------------------------------
// FastWaveNet autoregressive sampler v3c — persistent pipeline.
//   - weights as ext-vector SSA values (guaranteed VGPR residency)
//   - contiguous stamped record rows, single-asm wide-load polls
//   - ALL cross-block traffic at device coherence point (sc0 sc1) — the
//     R2-proven semantics; the R4 XCD fast path is reverted (suspect race)
//   - skip reduction in H1 (off the layer critical path)
// Arithmetic op order is bit-identical to round 2 (which passed absmax 0).
// ---------------------------------------------------------------------------

typedef unsigned long long u64;
typedef float v16 __attribute__((ext_vector_type(16)));

#define TT 1024

// byte offsets into d_ws
#define OFF_REC  4096                            // 29 layers * 256 rows * 128 B
#define OFF_SPR  (OFF_REC + 29*256*128)          // 256 rows * 256 u64
#define OFF_HID  (OFF_SPR + 256*256*8)           // 256 stamped hidden
#define OFF_IDX  (OFF_HID + 256*8)               // 1 stamped sampled index
#define OFF_XH   (OFF_IDX + 64)                  // 30*1024*256 f32 x history
#define WS_NEED  ((size_t)OFF_XH + (size_t)30*1024*256*4)

__device__ __forceinline__ long long rt(){
    return (long long)__builtin_amdgcn_s_memrealtime();
}
__device__ __forceinline__ u64 pk(unsigned stamp, float v){
    union { float f; unsigned u; } c; c.f = v;
    return ((u64)stamp << 32) | (u64)c.u;
}
__device__ __forceinline__ u64 pku(unsigned stamp, unsigned v){
    return ((u64)stamp << 32) | (u64)v;
}
__device__ __forceinline__ float uaf(unsigned u){
    union { unsigned u; float f; } c; c.u = u; return c.f;
}
__device__ __forceinline__ unsigned pst(u64 w){ return (unsigned)(w >> 32); }
// compiler agent-scope relaxed ops (R2-proven) for the x-history taps
__device__ __forceinline__ float ldf(const float* p){
    return __hip_atomic_load((float*)p, __ATOMIC_RELAXED, __HIP_MEMORY_SCOPE_AGENT);
}
__device__ __forceinline__ void stf(float* p, float v){
    __hip_atomic_store(p, v, __ATOMIC_RELAXED, __HIP_MEMORY_SCOPE_AGENT);
}

// ---- raw record ops — all device-coherent (sc0 sc1) ----
__device__ __forceinline__ u64 ld8_s(const void* p){
    u64 r;
    asm volatile("global_load_dwordx2 %0, %1, off sc0 sc1\n\ts_waitcnt vmcnt(0)"
                 : "=&v"(r) : "v"(p) : "memory");
    return r;
}
__device__ __forceinline__ void st8_s(void* p, u64 v){
    asm volatile("global_store_dwordx2 %0, %1, off sc0 sc1" :: "v"(p), "v"(v) : "memory");
}
__device__ __forceinline__ void poll5_s(const void* p, uint4& a, uint4& b, uint4& c,
                                        uint4& d, uint4& e){
    asm volatile(
        "global_load_dwordx4 %0, %5, off sc0 sc1\n\t"
        "global_load_dwordx4 %1, %5, off offset:16 sc0 sc1\n\t"
        "global_load_dwordx4 %2, %5, off offset:32 sc0 sc1\n\t"
        "global_load_dwordx4 %3, %5, off offset:48 sc0 sc1\n\t"
        "global_load_dwordx4 %4, %5, off offset:64 sc0 sc1\n\t"
        "s_waitcnt vmcnt(0)"
        : "=&v"(a),"=&v"(b),"=&v"(c),"=&v"(d),"=&v"(e) : "v"(p) : "memory");
}
__device__ __forceinline__ void poll4_s(const void* p, uint4& a, uint4& b, uint4& c,
                                        uint4& d){
    asm volatile(
        "global_load_dwordx4 %0, %4, off sc0 sc1\n\t"
        "global_load_dwordx4 %1, %4, off offset:16 sc0 sc1\n\t"
        "global_load_dwordx4 %2, %4, off offset:32 sc0 sc1\n\t"
        "global_load_dwordx4 %3, %4, off offset:48 sc0 sc1\n\t"
        "s_waitcnt vmcnt(0)"
        : "=&v"(a),"=&v"(b),"=&v"(c),"=&v"(d) : "v"(p) : "memory");
}
// LDS-only barrier (no vmcnt drain of in-flight global stores)
__device__ __forceinline__ void bar_lds(){
    asm volatile("s_waitcnt lgkmcnt(0)\n\ts_barrier" ::: "memory");
}

// ---- register-weight macros: plain brace blocks (safe to juxtapose) ----
#define LD16(W, P) { \
  W[0]=(P)[0]*one;  W[1]=(P)[1]*one;  W[2]=(P)[2]*one;  W[3]=(P)[3]*one;  \
  W[4]=(P)[4]*one;  W[5]=(P)[5]*one;  W[6]=(P)[6]*one;  W[7]=(P)[7]*one;  \
  W[8]=(P)[8]*one;  W[9]=(P)[9]*one;  W[10]=(P)[10]*one;W[11]=(P)[11]*one;\
  W[12]=(P)[12]*one;W[13]=(P)[13]*one;W[14]=(P)[14]*one;W[15]=(P)[15]*one;\
}

#define MAT16(W, X4, C, ACC) { \
  { float4 v_=(X4)[4*(C)+0]; ACC=fmaf(W[0],v_.x,ACC);  ACC=fmaf(W[1],v_.y,ACC);  ACC=fmaf(W[2],v_.z,ACC);  ACC=fmaf(W[3],v_.w,ACC); } \
  { float4 v_=(X4)[4*(C)+1]; ACC=fmaf(W[4],v_.x,ACC);  ACC=fmaf(W[5],v_.y,ACC);  ACC=fmaf(W[6],v_.z,ACC);  ACC=fmaf(W[7],v_.w,ACC); } \
  { float4 v_=(X4)[4*(C)+2]; ACC=fmaf(W[8],v_.x,ACC);  ACC=fmaf(W[9],v_.y,ACC);  ACC=fmaf(W[10],v_.z,ACC); ACC=fmaf(W[11],v_.w,ACC);} \
  { float4 v_=(X4)[4*(C)+3]; ACC=fmaf(W[12],v_.x,ACC); ACC=fmaf(W[13],v_.y,ACC); ACC=fmaf(W[14],v_.z,ACC); ACC=fmaf(W[15],v_.w,ACC);} \
}

// staggered WV load/matvec (identical element order to r2: chunk ci=(i+2q)&31)
#define LDWV1(W, I, E) { const float* p_ = rw + 4*(((I)+twoq)&31); \
  W[E+0]=p_[0]*one; W[E+1]=p_[1]*one; W[E+2]=p_[2]*one; W[E+3]=p_[3]*one; }
#define LDWV(W, K) LDWV1(W,4*(K)+0,0) LDWV1(W,4*(K)+1,4) LDWV1(W,4*(K)+2,8) LDWV1(W,4*(K)+3,12)
#define MATWV1(W, I, E, X4) { float4 v_=(X4)[(((I)+twoq)&31)]; \
  acc=fmaf(W[E+0],v_.x,acc); acc=fmaf(W[E+1],v_.y,acc); acc=fmaf(W[E+2],v_.z,acc); acc=fmaf(W[E+3],v_.w,acc); }
#define MATWV(W, K, X4) MATWV1(W,4*(K)+0,0,X4) MATWV1(W,4*(K)+1,4,X4) MATWV1(W,4*(K)+2,8,X4) MATWV1(W,4*(K)+3,12,X4)

#define MATZ1(W, I, E, ACC) { float4 v_=z4[(I)]; \
  ACC=fmaf(W[E+0],v_.x,ACC); ACC=fmaf(W[E+1],v_.y,ACC); ACC=fmaf(W[E+2],v_.z,ACC); ACC=fmaf(W[E+3],v_.w,ACC); }
#define MATZ(W, IB, ACC) MATZ1(W,(IB)+0,0,ACC) MATZ1(W,(IB)+1,4,ACC) MATZ1(W,(IB)+2,8,ACC) MATZ1(W,(IB)+3,12,ACC)

__global__ void __launch_bounds__(256, 1)
wavenet_v3c(const float* __restrict__ gy,   const float* __restrict__ gemb,
            const float* __restrict__ gcw,  const float* __restrict__ gwvp,
            const float* __restrict__ gwvx, const float* __restrict__ gwo,
            const float* __restrict__ gwob, const float* __restrict__ gwol,
            const float* __restrict__ gwobl,const float* __restrict__ ge1w,
            const float* __restrict__ ge1b, const float* __restrict__ ge2w,
            const float* __restrict__ ge2b, const float* __restrict__ gsmp,
            float one, int* __restrict__ gout, char* __restrict__ ws)
{
    const int b = blockIdx.x, tid = threadIdx.x;
    // layer j's 8 blocks share b&7 == j>>2 -> same XCD under round-robin (perf only)
    const int xcdh = b & 7, kk = b >> 3;
    const int jj = 4*xcdh + (kk >> 3);   // 0..29 layer, 30 head, 31 idle
    const int cc = kk & 7;
    if (jj > 30 || (jj == 30 && cc > 2)) return;

    u64* REC  = (u64*)(ws + OFF_REC);
    u64* SPR  = (u64*)(ws + OFF_SPR);
    u64* HIDP = (u64*)(ws + OFF_HID);
    u64* IDXP = (u64*)(ws + OFF_IDX);
    float* xh = (float*)(ws + OFF_XH);

    __shared__ float sTap[256];
    __shared__ float sXin[256];
    __shared__ float sY[80];
    __shared__ float sZ[32];
    __shared__ float sred[8];
    __shared__ int   sidx[4];

    const long long ddl = rt() + 400000000LL;       // watchdog: wrong, not hung

    // =======================================================================
    if (jj < 30){                                   // ---- layer block ----
        const int j   = jj;
        const int dil = 1 << (j % 10);
        const int q   = tid & 3;
        const int s   = (tid >> 2) & 15;
        const int w   = tid >> 6;
        const int twoq = 2*q;
        const int gr  = (s < 8) ? (32*cc + 8*w + s) : (256 + 32*cc + 8*w + (s - 8));

        const float* rw = (q < 2) ? (gwvp + ((size_t)j*512 + gr)*256 + 128*q)
                                  : (gwvx + ((size_t)j*512 + gr)*256 + 128*(q-2));
        v16 wv0,wv1,wv2,wv3,wv4,wv5,wv6,wv7;
        LDWV(wv0,0) LDWV(wv1,1) LDWV(wv2,2) LDWV(wv3,3)
        LDWV(wv4,4) LDWV(wv5,5) LDWV(wv6,6) LDWV(wv7,7)

        v16 cwa; float4 cwb;
        {
            const float* cp = gcw + ((size_t)(j*512 + gr))*80 + 20*q;
            LD16(cwa, cp);
            cwb.x = cp[16]*one; cwb.y = cp[17]*one; cwb.z = cp[18]*one; cwb.w = cp[19]*one;
        }
        const float* w0 = (j < 29) ? (gwo + ((size_t)j*512 + tid)*256 + 32*cc)
                                   : (gwol + (size_t)tid*256 + 32*cc);
        v16 wg0, wg1;
        LD16(wg0, w0); LD16(wg1, w0+16);
        v16 ws0, ws1;
        float bres = 0.f, bskip;
        if (j < 29){
            const float* w1 = gwo + ((size_t)j*512 + 256 + tid)*256 + 32*cc;
            LD16(ws0, w1); LD16(ws1, w1+16);
            bres  = gwob[j*512 + tid];
            bskip = gwob[j*512 + 256 + tid];
        } else {
            bskip = gwobl[tid];
        }

        u64* growp = REC + ((size_t)j*256 + tid)*16;          // my output row (j<=28)
        const char* pollb = (const char*)(REC + ((size_t)(j>0?j-1:0)*256 + tid)*16);
        u64* sprow = SPR + (size_t)tid*256 + (size_t)j*8 + cc;
        float* xhj = xh + (size_t)j*1024*256;
        float xv_prev = 0.f;

        for (int t = 0; t < TT; t++){
            const unsigned stamp = (unsigned)(t + 1);

            // ---- slack phase: stage cond column + dilated tap ----
            if (tid < 80) sY[tid] = gy[tid*TT + t];
            float tapv;
            if (dil == 1) tapv = xv_prev;
            else          tapv = (t >= dil) ? ldf(xhj + (size_t)(t-dil)*256 + tid) : 0.f;
            sTap[tid] = tapv;
            bar_lds();

            float acc = 0.f;
            {
                const float* yb = sY + 20*q;
                acc=fmaf(cwa[0],yb[0],acc);   acc=fmaf(cwa[1],yb[1],acc);
                acc=fmaf(cwa[2],yb[2],acc);   acc=fmaf(cwa[3],yb[3],acc);
                acc=fmaf(cwa[4],yb[4],acc);   acc=fmaf(cwa[5],yb[5],acc);
                acc=fmaf(cwa[6],yb[6],acc);   acc=fmaf(cwa[7],yb[7],acc);
                acc=fmaf(cwa[8],yb[8],acc);   acc=fmaf(cwa[9],yb[9],acc);
                acc=fmaf(cwa[10],yb[10],acc); acc=fmaf(cwa[11],yb[11],acc);
                acc=fmaf(cwa[12],yb[12],acc); acc=fmaf(cwa[13],yb[13],acc);
                acc=fmaf(cwa[14],yb[14],acc); acc=fmaf(cwa[15],yb[15],acc);
                acc=fmaf(cwb.x,yb[16],acc);   acc=fmaf(cwb.y,yb[17],acc);
                acc=fmaf(cwb.z,yb[18],acc);   acc=fmaf(cwb.w,yb[19],acc);
            }
            if (q < 2){                              // WV_past half: pre-poll
                const float4* x4p = (const float4*)(sTap + 128*q);
                MATWV(wv0,0,x4p) MATWV(wv1,1,x4p) MATWV(wv2,2,x4p) MATWV(wv3,3,x4p)
                MATWV(wv4,4,x4p) MATWV(wv5,5,x4p) MATWV(wv6,6,x4p) MATWV(wv7,7,x4p)
            }

            // ---- poll: one wide-load flight per iteration ----
            float xv;
            if (j == 0){
                if (t == 0){
                    xv = gemb[127*256 + tid];
                } else {
                    u64 wIdx; int c = 0;
                    do {
                        wIdx = ld8_s(IDXP);
                        if (((++c) & 255) == 0 && rt() > ddl) break;
                    } while (pst(wIdx) != (unsigned)t);
                    const int idx = (int)(wIdx & 0xffffffffu) & 255;
                    xv = gemb[idx*256 + tid];
                }
            } else {
                uint4 r0,r1,r2v,r3v,r4v; bool ok; int c = 0;
                do {
                    poll5_s(pollb, r0,r1,r2v,r3v,r4v);
                    ok = (r0.y==stamp) & (r0.w==stamp) & (r1.y==stamp) & (r1.w==stamp)
                       & (r2v.y==stamp) & (r2v.w==stamp) & (r3v.y==stamp) & (r3v.w==stamp)
                       & (r4v.y==stamp);
                    if (((++c) & 255) == 0 && rt() > ddl) break;
                } while (!ok);
                xv  = uaf(r4v.x);                    // x_{j-1} (slot 8)
                xv += uaf(r0.x);  xv += uaf(r0.z);   // cc0, cc1 (same order as r2)
                xv += uaf(r1.x);  xv += uaf(r1.z);
                xv += uaf(r2v.x); xv += uaf(r2v.z);
                xv += uaf(r3v.x); xv += uaf(r3v.z);
            }
            xv_prev = xv;
            sXin[tid] = xv;
            if (cc == 0){
                if (j <= 28) st8_s(growp + 8, pk(stamp, xv));       // x_j for j+1
                if (dil > 1) stf(&xhj[(size_t)t*256 + tid], xv);    // own future tap
            }
            bar_lds();

            if (q >= 2){                             // WV_present half: post-poll
                const float4* x4p = (const float4*)(sXin + 128*(q-2));
                MATWV(wv0,0,x4p) MATWV(wv1,1,x4p) MATWV(wv2,2,x4p) MATWV(wv3,3,x4p)
                MATWV(wv4,4,x4p) MATWV(wv5,5,x4p) MATWV(wv6,6,x4p) MATWV(wv7,7,x4p)
            }
            acc += __shfl_xor(acc, 1, 64);
            acc += __shfl_xor(acc, 2, 64);
            const float hpart = __shfl_xor(acc, 32, 64);
            if (q == 0 && s < 8)
                sZ[8*w + s] = tanhf(acc) * (1.f/(1.f + expf(-hpart)));
            bar_lds();

            const float4* z4 = (const float4*)sZ;
            if (j < 29){
                float g = 0.f, sk = 0.f;
                MATZ(wg0, 0, g)  MATZ(wg1, 4, g)
                MATZ(ws0, 0, sk) MATZ(ws1, 4, sk)
                if (cc == 0){ g += bres; sk += bskip; }
                st8_s(growp + cc, pk(stamp, g));
                st8_s(sprow, pk(stamp, sk));
            } else {
                float g = 0.f;
                MATZ(wg0, 0, g) MATZ(wg1, 4, g)
                if (cc == 0) g += bskip;
                st8_s(sprow, pk(stamp, g));
            }
        }
        return;
    }

    // =======================================================================
    if (jj == 30 && cc < 2){                        // ---- H1: end1 ----
        const int half = cc;
        const int r  = 128*half + (tid >> 1);
        const int hc = tid & 1;
        const float* wp = ge1w + (size_t)r*256 + 128*hc;
        v16 e0,e1v,e2v,e3,e4,e5,e6,e7;
        LD16(e0,wp);    LD16(e1v,wp+16); LD16(e2v,wp+32); LD16(e3,wp+48);
        LD16(e4,wp+64); LD16(e5,wp+80);  LD16(e6,wp+96);  LD16(e7,wp+112);
        const float b1 = ge1b[r];
        const u64* sprb = SPR + (size_t)tid*256;

        for (int t = 0; t < TT; t++){
            const unsigned stamp = (unsigned)(t + 1);
            // sum all 240 skip partials, layer-major cc-minor (same total
            // order as r2's SB chain -> bit-identical value)
            float sk = 0.f;
            for (int l = 0; l < 30; l++){
                uint4 r0,r1,r2v,r3v; bool ok; int c = 0;
                const void* p = (const void*)(sprb + l*8);
                do {
                    poll4_s(p, r0,r1,r2v,r3v);
                    ok = (r0.y==stamp)&(r0.w==stamp)&(r1.y==stamp)&(r1.w==stamp)
                       & (r2v.y==stamp)&(r2v.w==stamp)&(r3v.y==stamp)&(r3v.w==stamp);
                    if (((++c) & 255) == 0 && rt() > ddl) break;
                } while (!ok);
                sk += uaf(r0.x);  sk += uaf(r0.z);
                sk += uaf(r1.x);  sk += uaf(r1.z);
                sk += uaf(r2v.x); sk += uaf(r2v.z);
                sk += uaf(r3v.x); sk += uaf(r3v.z);
            }
            sTap[tid] = fmaxf(sk, 0.f);
            bar_lds();
            float a = 0.f;
            const float4* p4 = (const float4*)(sTap + 128*hc);
            MAT16(e0,p4,0,a)  MAT16(e1v,p4,1,a) MAT16(e2v,p4,2,a) MAT16(e3,p4,3,a)
            MAT16(e4,p4,4,a)  MAT16(e5,p4,5,a)  MAT16(e6,p4,6,a)  MAT16(e7,p4,7,a)
            a += __shfl_xor(a, 1, 64);
            if (hc == 0) st8_s(HIDP + r, pk(stamp, fmaxf(a + b1, 0.f)));
            bar_lds();
        }
        return;
    }

    // =======================================================================
    {                                               // ---- H2: end2 + sample ----
        const float* wp = ge2w + (size_t)tid*256;
        v16 f0,f1,f2,f3,f4,f5,f6,f7,f8,f9,fa,fb,fc,fd,fe,ff;
        LD16(f0,wp);     LD16(f1,wp+16);  LD16(f2,wp+32);  LD16(f3,wp+48);
        LD16(f4,wp+64);  LD16(f5,wp+80);  LD16(f6,wp+96);  LD16(f7,wp+112);
        LD16(f8,wp+128); LD16(f9,wp+144); LD16(fa,wp+160); LD16(fb,wp+176);
        LD16(fc,wp+192); LD16(fd,wp+208); LD16(fe,wp+224); LD16(ff,wp+240);
        const float b2 = ge2b[tid];
        const int w = tid >> 6, lane = tid & 63;

        for (int t = 0; t < TT; t++){
            const unsigned stamp = (unsigned)(t + 1);
            u64 hw; int c = 0;
            do {
                hw = ld8_s(HIDP + tid);
                if (((++c) & 255) == 0 && rt() > ddl) break;
            } while (pst(hw) != stamp);
            sTap[tid] = uaf((unsigned)(hw & 0xffffffffu));
            bar_lds();
            float a = b2;
            const float4* p4 = (const float4*)sTap;
            MAT16(f0,p4,0,a)  MAT16(f1,p4,1,a)  MAT16(f2,p4,2,a)  MAT16(f3,p4,3,a)
            MAT16(f4,p4,4,a)  MAT16(f5,p4,5,a)  MAT16(f6,p4,6,a)  MAT16(f7,p4,7,a)
            MAT16(f8,p4,8,a)  MAT16(f9,p4,9,a)  MAT16(fa,p4,10,a) MAT16(fb,p4,11,a)
            MAT16(fc,p4,12,a) MAT16(fd,p4,13,a) MAT16(fe,p4,14,a) MAT16(ff,p4,15,a)
            // softmax + cumsum + first cum > u (identical op order to r2)
            float m = a;
            #pragma unroll
            for (int off = 32; off > 0; off >>= 1) m = fmaxf(m, __shfl_xor(m, off, 64));
            if (lane == 0) sred[w] = m;
            bar_lds();
            m = fmaxf(fmaxf(sred[0], sred[1]), fmaxf(sred[2], sred[3]));
            float pe = expf(a - m);
            float ssum = pe;
            #pragma unroll
            for (int off = 32; off > 0; off >>= 1) ssum += __shfl_xor(ssum, off, 64);
            if (lane == 0) sred[4 + w] = ssum;
            bar_lds();
            const float S = sred[4] + sred[5] + sred[6] + sred[7];
            float cum = pe / S;
            #pragma unroll
            for (int off = 1; off < 64; off <<= 1){
                float vv = __shfl_up(cum, off, 64);
                if (lane >= off) cum += vv;
            }
            if (lane == 63) sred[w] = cum;
            bar_lds();
            float base = 0.f;
            if (w > 0) base += sred[0];
            if (w > 1) base += sred[1];
            if (w > 2) base += sred[2];
            cum += base;
            const float u = gsmp[t];
            unsigned long long bal = __ballot(cum > u);
            int cand = bal ? (w*64 + __ffsll((long long)bal) - 1) : (1 << 30);
            if (lane == 0) sidx[w] = cand;
            bar_lds();
            int idx = min(min(sidx[0], sidx[1]), min(sidx[2], sidx[3]));
            if (idx > 255) idx = 0;
            if (tid == 0){
                gout[t] = idx;
                st8_s(IDXP, pku(stamp, (unsigned)idx));   // feedback to layer 0
            }
            bar_lds();
        }
        return;
    }
}

__global__ void ws_too_small_kernel(int* out, int n){
    int i = blockIdx.x*256 + threadIdx.x;
    if (i < n) out[i] = 0;
}

extern "C" void kernel_launch(void* const* d_in, const int* in_sizes, int n_in,
                              void* d_out, int out_size, void* d_ws, size_t ws_size,
                              hipStream_t stream){
    (void)in_sizes; (void)n_in;
    if (ws_size < WS_NEED){
        hipLaunchKernelGGL(ws_too_small_kernel, dim3(4), dim3(256), 0, stream,
                           (int*)d_out, out_size);
        return;
    }
    hipLaunchKernelGGL(wavenet_v3c, dim3(256), dim3(256), 0, stream,
                       (const float*)d_in[0],  (const float*)d_in[1],
                       (const float*)d_in[2],  (const float*)d_in[3],
                       (const float*)d_in[4],  (const float*)d_in[5],
                       (const float*)d_in[6],  (const float*)d_in[7],
                       (const float*)d_in[8],  (const float*)d_in[9],
                       (const float*)d_in[10], (const float*)d_in[11],
                       (const float*)d_in[12], (const float*)d_in[13],
                       1.0f, (int*)d_out, (char*)d_ws);
}